// Round 7
// baseline (70.210 us; speedup 1.0000x reference)
//
#include <hip/hip_runtime.h>
#include <hip/hip_cooperative_groups.h>
#include <stdint.h>

namespace cg = cooperative_groups;

#define BATCH 32
#define NA    8400
#define NL    80
#define NH    256
#define NK    300
#define NBIN  8192   // 13-bit key = mapped-u32 >> 19
#define RPB   1050   // rows per block (NA/8)

// output float offsets (concatenated return order)
#define OUT0 0                       // init_reference_points (32,300,4)
#define OUT1 38400                   // target                (32,300,256)
#define OUT2 2496000                 // enc_topk_logits       (32,300,80)
#define OUT3 3264000                 // enc_topk_bboxes       (32,300,4)

__device__ __forceinline__ unsigned mapf(float f) {
    unsigned u = __float_as_uint(f);
    return (u & 0x80000000u) ? ~u : (u | 0x80000000u);
}

// Single cooperative kernel: 256 blocks x 1024 threads (1 block/CU).
// Block (b = bid&31, sub = bid>>5):
//   phase 1: max over L=80 for rows [sub*1050, (sub+1)*1050) of batch b -> ws_u
//   grid sync
//   phase 2: redundant exact top-300 select of batch b (LDS hist + scan +
//            rank-by-comparison), then gather queries q ≡ sub (mod 8).
// The 8 blocks of batch b have bids ≡ b (mod 8) -> same XCD round-robin slot,
// so ws_u[b] has L2 locality across phases (perf bonus only; grid.sync owns
// correctness).
__global__ __launch_bounds__(1024) void fused_kernel(
        const float*    __restrict__ cls,
        const float*    __restrict__ coord,
        const float*    __restrict__ mem,
        unsigned*       __restrict__ ws_u,
        float*          __restrict__ out) {
    __shared__ unsigned hist[NBIN];                 // 32 KB
    __shared__ unsigned long long keys[1024];       // 8 KB
    __shared__ int ord[NK];
    __shared__ unsigned wsum[16], wsuf[16];
    __shared__ unsigned s_thr, s_count;

    int tid  = threadIdx.x;
    int lane = tid & 63;
    int wid  = tid >> 6;
    int b    = blockIdx.x & 31;
    int sub  = blockIdx.x >> 5;                     // 0..7

    // ---- phase 1: class-max for this block's 1050-row slice ----
    {
        int r4 = tid >> 2;                          // 0..255
        int s4 = tid & 3;
        size_t rowbase = (size_t)b * NA + (size_t)sub * RPB;
#pragma unroll
        for (int p = 0; p < 5; ++p) {
            int r = p * 256 + r4;
            if (r < RPB) {
                const float4* rp = (const float4*)(cls + (rowbase + r) * NL) + s4 * 5;
                float m = -3.4e38f;
#pragma unroll
                for (int e = 0; e < 5; ++e) {
                    float4 w = rp[e];
                    m = fmaxf(m, fmaxf(fmaxf(w.x, w.y), fmaxf(w.z, w.w)));
                }
                m = fmaxf(m, __shfl_xor(m, 1));
                m = fmaxf(m, __shfl_xor(m, 2));
                if (s4 == 0) ws_u[rowbase + r] = mapf(m);
            }
        }
    }

    cg::this_grid().sync();

    // ---- phase 2: select + gather (identical to round-5/6 passing code) ----
    const unsigned* ub = ws_u + b * NA;

    // issue global loads FIRST (latency hides under hist zeroing)
    unsigned v[9];
#pragma unroll
    for (int k = 0; k < 9; ++k) {
        int i = tid + k * 1024;
        v[k] = (i < NA) ? ub[i] : 0u;               // 0 -> bin 0, never selected
    }

    for (int i = tid; i < NBIN; i += 1024) hist[i] = 0;
    if (tid == 0) s_count = 0;
    __syncthreads();

#pragma unroll
    for (int k = 0; k < 9; ++k) {
        int i = tid + k * 1024;
        if (i < NA) atomicAdd(&hist[v[k] >> 19], 1u);
    }
    __syncthreads();

    // hierarchical suffix scan over 8192 bins; thread owns [tid*8, tid*8+8)
    unsigned base = tid * 8;
    unsigned h[8];
#pragma unroll
    for (int j = 0; j < 8; ++j) h[j] = hist[base + j];
    unsigned L = 0;
#pragma unroll
    for (int j = 0; j < 8; ++j) L += h[j];
    unsigned s = L;                                  // inclusive suffix within wave
#pragma unroll
    for (int off = 1; off < 64; off <<= 1) {
        unsigned t = __shfl_down(s, off);
        if (lane + off < 64) s += t;
    }
    if (lane == 0) wsum[wid] = s;
    __syncthreads();
    if (tid == 0) {
        unsigned acc = 0;
        for (int w = 15; w >= 0; --w) { acc += wsum[w]; wsuf[w] = acc; }
    }
    __syncthreads();
    unsigned above = (wid < 15 ? wsuf[wid + 1] : 0u) + (s - L);
    unsigned acc = above;
#pragma unroll
    for (int j = 7; j >= 0; --j) {
        unsigned S = acc + h[j];
        if (S >= (unsigned)NK && acc < (unsigned)NK) s_thr = base + (unsigned)j;
        acc = S;
    }
    __syncthreads();

    // collect candidates from registers (no global re-read)
    unsigned T = s_thr;
#pragma unroll
    for (int k = 0; k < 9; ++k) {
        int i = tid + k * 1024;
        if (i < NA && (v[k] >> 19) >= T) {
            unsigned pos = atomicAdd(&s_count, 1u);
            if (pos < 1024) keys[pos] = ((unsigned long long)(~v[k]) << 32) | (unsigned)i;
        }
    }
    __syncthreads();

    // rank-by-comparison: key asc == (u desc, idx asc); deterministic
    unsigned count = s_count < 1024u ? s_count : 1024u;
    if (tid < (int)count) {
        unsigned long long mykey = keys[tid];
        int rank = 0;
        for (unsigned j = 0; j < count; ++j) rank += (keys[j] < mykey);
        if (rank < NK) ord[rank] = (int)(mykey & 0xFFFFFFFFull);
    }
    __syncthreads();

    // gather: this block handles queries q ≡ sub (mod 8); one wave per query
    for (int q = sub + 8 * wid; q < NK; q += 8 * 16) {
        int idx = ord[q];
        size_t srow = (size_t)b * NA + (size_t)idx;
        size_t drow = (size_t)b * NK + (size_t)q;

        const float4* msrc = (const float4*)(mem + srow * NH);
        float4*       mdst = (float4*)(out + OUT1 + drow * NH);
        mdst[lane] = msrc[lane];

        if (lane < 20) {
            const float4* lsrc = (const float4*)(cls + srow * NL);
            float4*       ldst = (float4*)(out + OUT2 + drow * NL);
            ldst[lane] = lsrc[lane];
        }
        if (lane == 0) {
            float4 c = ((const float4*)(coord + srow * 4))[0];
            ((float4*)(out + OUT0 + drow * 4))[0] = c;
            float4 sg;
            sg.x = 1.0f / (1.0f + __expf(-c.x));
            sg.y = 1.0f / (1.0f + __expf(-c.y));
            sg.z = 1.0f / (1.0f + __expf(-c.z));
            sg.w = 1.0f / (1.0f + __expf(-c.w));
            ((float4*)(out + OUT3 + drow * 4))[0] = sg;
        }
    }
}

extern "C" void kernel_launch(void* const* d_in, const int* in_sizes, int n_in,
                              void* d_out, int out_size, void* d_ws, size_t ws_size,
                              hipStream_t stream) {
    const float* cls   = (const float*)d_in[0]; // (32,8400,80)
    const float* coord = (const float*)d_in[1]; // (32,8400,4)
    const float* mem   = (const float*)d_in[2]; // (32,8400,256)
    // d_in[3] (sources_last_element) unused by the reference

    unsigned* ws_u = (unsigned*)d_ws;           // 32*8400 u32
    float*    out  = (float*)d_out;

    void* args[] = {(void*)&cls, (void*)&coord, (void*)&mem,
                    (void*)&ws_u, (void*)&out};
    hipLaunchCooperativeKernel((const void*)fused_kernel,
                               dim3(256), dim3(1024), args, 0, stream);
}